// Round 9
// baseline (97.677 us; speedup 1.0000x reference)
//
#include <hip/hip_runtime.h>
#include <hip/hip_bf16.h>

#define NE 100000
#define NK 16
#define ND 128
#define NTILES 6250   // NE / 16

typedef __bf16 bf16_t;
typedef bf16_t bf16x8 __attribute__((ext_vector_type(8)));
typedef bf16_t bf16x4 __attribute__((ext_vector_type(4)));
typedef float f32x4 __attribute__((ext_vector_type(4)));
typedef float f32x2 __attribute__((ext_vector_type(2)));
typedef unsigned short u16;
typedef unsigned char u8;

__device__ __forceinline__ u16 f2bf(float f) {
  bf16_t h = (bf16_t)f;
  return __builtin_bit_cast(u16, h);
}

// ---------------------------------------------------------------------------
// k_prep: bf16-convert weights; fold Wp = Um@mW2, bp = ub1 + Um@mb2.
// ---------------------------------------------------------------------------
__global__ void k_prep(const float* __restrict__ mW1, const float* __restrict__ uW1,
                       const float* __restrict__ uW2, const float* __restrict__ mW2,
                       const float* __restrict__ ub1, const float* __restrict__ mb2,
                       u16* __restrict__ Wi_b, u16* __restrict__ Wj_b,
                       u16* __restrict__ Ui_b, u16* __restrict__ Wp_b,
                       u16* __restrict__ W2_b, float* __restrict__ bp)
{
  const int o = blockIdx.x, t = threadIdx.x;
  Wi_b[o * ND + t] = f2bf(mW1[o * 256 + t]);
  Wj_b[o * ND + t] = f2bf(mW1[o * 256 + 128 + t]);
  Ui_b[o * ND + t] = f2bf(uW1[o * 256 + t]);
  W2_b[o * ND + t] = f2bf(uW2[o * ND + t]);
  float acc = 0.f;
  for (int p = 0; p < 128; ++p)
    acc += uW1[o * 256 + 128 + p] * mW2[p * 128 + t];
  Wp_b[o * ND + t] = f2bf(acc);
  if (t == 0) {
    float b = ub1[o];
    for (int p = 0; p < 128; ++p) b += uW1[o * 256 + 128 + p] * mb2[p];
    bp[o] = b;
  }
}

// ---------------------------------------------------------------------------
// k1: S = X@Wi^T + mb1 (bf16), Z = X@Wj^T (fp8 e4m3), T1 = X@Ui^T + bp
// (bf16 in out rows, u16-stride 256). 512 threads / 8 waves; wave w owns
// col-tile w. r9: ONE barrier per tile — X tile and epilogue tiles are
// double-buffered; stage of tile t+1 goes to xt[b^1] while frags of tile t
// are read from xt[b] (no hazard), epilogue write e[b] is separated from
// its read by the single barrier; buffer reuse is 2 barriers apart.
// ---------------------------------------------------------------------------
__global__ __launch_bounds__(512) void k1_szt(
    const float* __restrict__ X, const u16* __restrict__ Wi_b,
    const u16* __restrict__ Wj_b, const u16* __restrict__ Ui_b,
    const float* __restrict__ mb1, const float* __restrict__ bp,
    u16* __restrict__ Sb, u8* __restrict__ Zf8, u16* __restrict__ T1)
{
  __shared__ u16 xt[2][16 * ND];   // 2 x 4 KB X tile (bf16, swizzled)
  __shared__ u16 eS[2][16 * ND];   // 2 x 4 KB epilogue S
  __shared__ u8  eZ[2][16 * ND];   // 2 x 2 KB epilogue Z (fp8)
  __shared__ u16 eT[2][16 * ND];   // 2 x 4 KB epilogue T1
  const int tid = threadIdx.x, wid = tid >> 6, lane = tid & 63;
  const int r = lane & 15, q = lane >> 4;

  bf16x8 wiF[4], wjF[4], uiF[4];
  f32x4 mbF, bpF;
  {
    const int row = wid * 16 + r;
#pragma unroll
    for (int kk = 0; kk < 4; ++kk) {
      wiF[kk] = *(const bf16x8*)(Wi_b + row * ND + kk * 32 + q * 8);
      wjF[kk] = *(const bf16x8*)(Wj_b + row * ND + kk * 32 + q * 8);
      uiF[kk] = *(const bf16x8*)(Ui_b + row * ND + kk * 32 + q * 8);
    }
    mbF = *(const f32x4*)(mb1 + wid * 16 + q * 4);
    bpF = *(const f32x4*)(bp  + wid * 16 + q * 4);
  }

  // staging coords (X tile): thread -> (row rs, f32x4 chunk cs)
  const int rs = tid >> 5, cs = tid & 31;
  const int stb = rs * 256 + ((((cs >> 1) ^ (rs & 15)) << 4) | ((cs & 1) << 3));
  // epilogue write coords (lane: edge r, ch base wid*16+q*4)
  const int ewb = r * 256 + ((((wid * 2 + (q >> 1)) ^ (r & 15)) << 4) | ((q & 1) << 3));
  const int ezb = r * 128 + (((wid ^ (r & 7)) << 4) | (q * 4));
  // epilogue read coords
  const int erow = tid >> 5, c8 = tid & 31;
  const int erb = erow * 256 + ((((c8 >> 1) ^ (erow & 15)) << 4) | ((c8 & 1) << 3));
  const int zrb = erow * 128 + ((((c8 >> 2) ^ (erow & 7)) << 4) | ((c8 & 3) << 2));

  const long stride = gridDim.x;
  long t = blockIdx.x;
  if (t >= NTILES) return;

  f32x4 xr;
  auto gload = [&](long tt) {
    xr = *(const f32x4*)(X + (tt * 16 + rs) * ND + cs * 4);
  };
  auto stage = [&](int bb) {
    bf16x4 b;
#pragma unroll
    for (int i = 0; i < 4; ++i) b[i] = (bf16_t)xr[i];
    *(bf16x4*)((char*)xt[bb] + stb) = b;
  };

  // prologue: tile t staged into xt[0]; xr holds tile t+stride
  gload(t);
  stage(0);
  {
    const long t1 = t + stride;
    if (t1 < NTILES) gload(t1);
  }
  __syncthreads();
  int b = 0;

  for (; t < NTILES; t += stride) {
    const long tn = t + stride, tn2 = tn + stride;

    bf16x8 xf[4];
#pragma unroll
    for (int kk = 0; kk < 4; ++kk)
      xf[kk] = *(const bf16x8*)((const char*)xt[b] +
               r * 256 + (((kk * 4 + q) ^ (r & 15)) << 4));

    if (tn < NTILES) stage(b ^ 1);   // consumes xr (tile tn), other buffer
    if (tn2 < NTILES) gload(tn2);    // refill xr; covered by MFMA+stores

    f32x4 aS = {0.f, 0.f, 0.f, 0.f};
    f32x4 aZ = {0.f, 0.f, 0.f, 0.f};
    f32x4 aT = {0.f, 0.f, 0.f, 0.f};
#pragma unroll
    for (int kk = 0; kk < 4; ++kk) {
      aS = __builtin_amdgcn_mfma_f32_16x16x32_bf16(wiF[kk], xf[kk], aS, 0, 0, 0);
      aZ = __builtin_amdgcn_mfma_f32_16x16x32_bf16(wjF[kk], xf[kk], aZ, 0, 0, 0);
      aT = __builtin_amdgcn_mfma_f32_16x16x32_bf16(uiF[kk], xf[kk], aT, 0, 0, 0);
    }

    bf16x4 pS, pT;
#pragma unroll
    for (int i = 0; i < 4; ++i) {
      pS[i] = (bf16_t)(aS[i] + mbF[i]);
      pT[i] = (bf16_t)(aT[i] + bpF[i]);
    }
    unsigned zpk = 0;
    zpk = __builtin_amdgcn_cvt_pk_fp8_f32(aZ[0], aZ[1], zpk, false);
    zpk = __builtin_amdgcn_cvt_pk_fp8_f32(aZ[2], aZ[3], zpk, true);
    *(bf16x4*)((char*)eS[b] + ewb) = pS;
    *(bf16x4*)((char*)eT[b] + ewb) = pT;
    *(unsigned*)((char*)eZ[b] + ezb) = zpk;

    __syncthreads();   // the ONLY barrier: e[b] visible; xt[b^1] staged

    {
      const long e = t * 16 + erow;
      const bf16x4 vS = *(const bf16x4*)((const char*)eS[b] + erb);
      const bf16x4 vT = *(const bf16x4*)((const char*)eT[b] + erb);
      const unsigned vZ = *(const unsigned*)((const char*)eZ[b] + zrb);
      *(bf16x4*)(Sb + e * ND + c8 * 4) = vS;
      *(bf16x4*)(T1 + e * 256 + c8 * 4) = vT;
      *(unsigned*)(Zf8 + e * ND + c8 * 4) = vZ;
    }
    b ^= 1;
  }
}

// ---------------------------------------------------------------------------
// k2: hbar[e] = (1/16) * sum_k relu(S[e] + Z[adj[e][k]]), Z in fp8 e4m3.
// Wave = 2 edges: half-wave per edge, lane covers 4 channels (1 dword fp8).
// (Round-7 version verbatim — control.)
// ---------------------------------------------------------------------------
__global__ __launch_bounds__(256) void k2_gather(
    const u8* __restrict__ Zf8, const u16* __restrict__ Sb,
    const int* __restrict__ adj, u16* __restrict__ Hb)
{
  const int tid = threadIdx.x, w4 = tid >> 6, lane = tid & 63;
  const int sub = lane >> 5, l = lane & 31;
  const long e = (long)blockIdx.x * 8 + w4 * 2 + sub;
  const int c0 = l * 4;

  const bf16x4 sv = *(const bf16x4*)(Sb + e * ND + c0);
  f32x4 s;
#pragma unroll
  for (int i = 0; i < 4; ++i) s[i] = (float)sv[i];

  const int myidx = adj[e * NK + (lane & 15)];

  f32x4 acc = {0.f, 0.f, 0.f, 0.f};
#pragma unroll
  for (int k = 0; k < NK; ++k) {
    const int n = __shfl(myidx, (lane & 32) + k);
    const unsigned zw = *(const unsigned*)(Zf8 + (long)n * ND + c0);
    const f32x2 zlo = __builtin_amdgcn_cvt_pk_f32_fp8(zw, false);
    const f32x2 zhi = __builtin_amdgcn_cvt_pk_f32_fp8(zw, true);
    f32x4 z;
    z[0] = zlo[0]; z[1] = zlo[1]; z[2] = zhi[0]; z[3] = zhi[1];
    f32x4 v = s + z;
#pragma unroll
    for (int i = 0; i < 4; ++i) v[i] = fmaxf(v[i], 0.f);
    acc += v;
  }

  bf16x4 hv;
#pragma unroll
  for (int i = 0; i < 4; ++i) hv[i] = (bf16_t)(acc[i] * 0.0625f);
  *(bf16x4*)(Hb + e * ND + c0) = hv;
}

// ---------------------------------------------------------------------------
// k3: u = relu(T1 + Hb@Wp^T); out = u@uW2^T + ub2. (Round-7 verbatim.)
// ---------------------------------------------------------------------------
__global__ __launch_bounds__(512) void k3_out(
    const u16* __restrict__ Hb, const u16* __restrict__ T1,
    const u16* __restrict__ Wp_b, const u16* __restrict__ W2_b,
    const float* __restrict__ ub2, float* __restrict__ out)
{
  __shared__ u16 ht[16 * ND];
  __shared__ u16 ut[16 * ND];
  const int tid = threadIdx.x, wid = tid >> 6, lane = tid & 63;
  const int r = lane & 15, q = lane >> 4;

  bf16x8 wpF[4], w2F[4];
  f32x4 ubF;
  {
    const int row = wid * 16 + r;
#pragma unroll
    for (int kk = 0; kk < 4; ++kk) {
      wpF[kk] = *(const bf16x8*)(Wp_b + row * ND + kk * 32 + q * 8);
      w2F[kk] = *(const bf16x8*)(W2_b + row * ND + kk * 32 + q * 8);
    }
    ubF = *(const f32x4*)(ub2 + wid * 16 + q * 4);
  }

  const int rs = tid >> 5, cs = tid & 31;
  const int stb = rs * 256 + ((((cs >> 1) ^ (rs & 15)) << 4) | ((cs & 1) << 3));

  const long stride = gridDim.x;
  long t = blockIdx.x;
  if (t >= NTILES) return;

  bf16x4 hr;
  auto gload = [&](long tt) {
    hr = *(const bf16x4*)(Hb + (tt * 16 + rs) * ND + cs * 4);
  };
  gload(t);
  *(bf16x4*)((char*)ht + stb) = hr;
  __syncthreads();

  for (; t < NTILES; t += stride) {
    const long tn = t + stride;
    if (tn < NTILES) gload(tn);

    bf16x8 hf[4];
#pragma unroll
    for (int kk = 0; kk < 4; ++kk)
      hf[kk] = *(const bf16x8*)((const char*)ht +
               r * 256 + (((kk * 4 + q) ^ (r & 15)) << 4));

    f32x4 acc;
    {
      const bf16x4 tv = *(const bf16x4*)(T1 + (t * 16 + r) * 256 + wid * 16 + q * 4);
#pragma unroll
      for (int i = 0; i < 4; ++i) acc[i] = (float)tv[i];
    }
#pragma unroll
    for (int kk = 0; kk < 4; ++kk)
      acc = __builtin_amdgcn_mfma_f32_16x16x32_bf16(wpF[kk], hf[kk], acc, 0, 0, 0);

    bf16x4 u;
#pragma unroll
    for (int i = 0; i < 4; ++i) u[i] = (bf16_t)fmaxf(acc[i], 0.f);
    const int uwb = r * 256 + ((((wid * 2 + (q >> 1)) ^ (r & 15)) << 4) | ((q & 1) << 3));

    __syncthreads();
    *(bf16x4*)((char*)ut + uwb) = u;
    if (tn < NTILES) *(bf16x4*)((char*)ht + stb) = hr;
    __syncthreads();

    bf16x8 uf[4];
#pragma unroll
    for (int kk = 0; kk < 4; ++kk)
      uf[kk] = *(const bf16x8*)((const char*)ut +
               r * 256 + (((kk * 4 + q) ^ (r & 15)) << 4));

    f32x4 o = {0.f, 0.f, 0.f, 0.f};
#pragma unroll
    for (int kk = 0; kk < 4; ++kk)
      o = __builtin_amdgcn_mfma_f32_16x16x32_bf16(w2F[kk], uf[kk], o, 0, 0, 0);
#pragma unroll
    for (int i = 0; i < 4; ++i) o[i] += ubF[i];
    *(f32x4*)(out + (t * 16 + r) * ND + wid * 16 + q * 4) = o;
  }
}

extern "C" void kernel_launch(void* const* d_in, const int* in_sizes, int n_in,
                              void* d_out, int out_size, void* d_ws, size_t ws_size,
                              hipStream_t stream)
{
  (void)in_sizes; (void)n_in; (void)out_size; (void)ws_size;
  const float* X   = (const float*)d_in[0];
  const int*   adj = (const int*)d_in[1];
  const float* mW1 = (const float*)d_in[2];
  const float* mb1 = (const float*)d_in[3];
  const float* mW2 = (const float*)d_in[4];
  const float* mb2 = (const float*)d_in[5];
  const float* uW1 = (const float*)d_in[6];
  const float* ub1 = (const float*)d_in[7];
  const float* uW2 = (const float*)d_in[8];
  const float* ub2 = (const float*)d_in[9];
  float* out = (float*)d_out;

  u16* ws16 = (u16*)d_ws;
  u16* Sb   = ws16;                              // E*D bf16 (25.6 MB)
  u16* Hb   = Sb + (size_t)NE * ND;              // E*D bf16 (25.6 MB)
  u8*  Zf8  = (u8*)(Hb + (size_t)NE * ND);       // E*D fp8  (12.8 MB)
  u16* Wi_b = (u16*)(Zf8 + (size_t)NE * ND);     // 128*128 bf16 each:
  u16* Wj_b = Wi_b + 128 * 128;
  u16* Ui_b = Wj_b + 128 * 128;
  u16* Wp_b = Ui_b + 128 * 128;
  u16* W2_b = Wp_b + 128 * 128;
  float* bp = (float*)(W2_b + 128 * 128);        // 128 f32
  u16* T1   = (u16*)d_out;                       // bf16 T1, stride 256, in out rows

  k_prep<<<128, 128, 0, stream>>>(mW1, uW1, uW2, mW2, ub1, mb2,
                                  Wi_b, Wj_b, Ui_b, Wp_b, W2_b, bp);

  k1_szt<<<1024, 512, 0, stream>>>(X, Wi_b, Wj_b, Ui_b, mb1, bp, Sb, Zf8, T1);

  k2_gather<<<NE / 8, 256, 0, stream>>>(Zf8, Sb, adj, Hb);

  k3_out<<<1024, 512, 0, stream>>>(Hb, T1, Wp_b, W2_b, ub2, out);
}

// Round 10
// 95.231 us; speedup vs baseline: 1.0257x; 1.0257x over previous
//
#include <hip/hip_runtime.h>
#include <hip/hip_bf16.h>

#define NE 100000
#define NK 16
#define ND 128
#define NTILES 6250   // NE / 16

typedef __bf16 bf16_t;
typedef bf16_t bf16x8 __attribute__((ext_vector_type(8)));
typedef bf16_t bf16x4 __attribute__((ext_vector_type(4)));
typedef float f32x4 __attribute__((ext_vector_type(4)));
typedef float f32x2 __attribute__((ext_vector_type(2)));
typedef unsigned u32x2 __attribute__((ext_vector_type(2)));
typedef unsigned short u16;
typedef unsigned char u8;

__device__ __forceinline__ u16 f2bf(float f) {
  bf16_t h = (bf16_t)f;
  return __builtin_bit_cast(u16, h);
}

// ---------------------------------------------------------------------------
// k_prep: bf16-convert weights; fold Wp = Um@mW2, bp = ub1 + Um@mb2.
// ---------------------------------------------------------------------------
__global__ void k_prep(const float* __restrict__ mW1, const float* __restrict__ uW1,
                       const float* __restrict__ uW2, const float* __restrict__ mW2,
                       const float* __restrict__ ub1, const float* __restrict__ mb2,
                       u16* __restrict__ Wi_b, u16* __restrict__ Wj_b,
                       u16* __restrict__ Ui_b, u16* __restrict__ Wp_b,
                       u16* __restrict__ W2_b, float* __restrict__ bp)
{
  const int o = blockIdx.x, t = threadIdx.x;
  Wi_b[o * ND + t] = f2bf(mW1[o * 256 + t]);
  Wj_b[o * ND + t] = f2bf(mW1[o * 256 + 128 + t]);
  Ui_b[o * ND + t] = f2bf(uW1[o * 256 + t]);
  W2_b[o * ND + t] = f2bf(uW2[o * ND + t]);
  float acc = 0.f;
  for (int p = 0; p < 128; ++p)
    acc += uW1[o * 256 + 128 + p] * mW2[p * 128 + t];
  Wp_b[o * ND + t] = f2bf(acc);
  if (t == 0) {
    float b = ub1[o];
    for (int p = 0; p < 128; ++p) b += uW1[o * 256 + 128 + p] * mb2[p];
    bp[o] = b;
  }
}

// ---------------------------------------------------------------------------
// k1: S = X@Wi^T + mb1 (bf16), Z = X@Wj^T (fp8 e4m3), T1 = X@Ui^T + bp
// (bf16, PACKED per-tile into the first 4 KB of each tile's 8 KB out region
// -> fully-contiguous 4 KB write here, coalesced staged read in k3).
// 512 threads / 8 waves; wave w owns col-tile w. One barrier per tile
// (double-buffered X tile + epilogue tiles, r9 structure).
// ---------------------------------------------------------------------------
__global__ __launch_bounds__(512) void k1_szt(
    const float* __restrict__ X, const u16* __restrict__ Wi_b,
    const u16* __restrict__ Wj_b, const u16* __restrict__ Ui_b,
    const float* __restrict__ mb1, const float* __restrict__ bp,
    u16* __restrict__ Sb, u8* __restrict__ Zf8, u16* __restrict__ Tp)
{
  __shared__ u16 xt[2][16 * ND];   // 2 x 4 KB X tile (bf16, swizzled)
  __shared__ u16 eS[2][16 * ND];   // 2 x 4 KB epilogue S
  __shared__ u8  eZ[2][16 * ND];   // 2 x 2 KB epilogue Z (fp8)
  __shared__ u16 eT[2][16 * ND];   // 2 x 4 KB epilogue T1
  const int tid = threadIdx.x, wid = tid >> 6, lane = tid & 63;
  const int r = lane & 15, q = lane >> 4;

  bf16x8 wiF[4], wjF[4], uiF[4];
  f32x4 mbF, bpF;
  {
    const int row = wid * 16 + r;
#pragma unroll
    for (int kk = 0; kk < 4; ++kk) {
      wiF[kk] = *(const bf16x8*)(Wi_b + row * ND + kk * 32 + q * 8);
      wjF[kk] = *(const bf16x8*)(Wj_b + row * ND + kk * 32 + q * 8);
      uiF[kk] = *(const bf16x8*)(Ui_b + row * ND + kk * 32 + q * 8);
    }
    mbF = *(const f32x4*)(mb1 + wid * 16 + q * 4);
    bpF = *(const f32x4*)(bp  + wid * 16 + q * 4);
  }

  const int rs = tid >> 5, cs = tid & 31;
  const int stb = rs * 256 + ((((cs >> 1) ^ (rs & 15)) << 4) | ((cs & 1) << 3));
  const int ewb = r * 256 + ((((wid * 2 + (q >> 1)) ^ (r & 15)) << 4) | ((q & 1) << 3));
  const int ezb = r * 128 + (((wid ^ (r & 7)) << 4) | (q * 4));
  const int erow = tid >> 5, c8 = tid & 31;
  const int erb = erow * 256 + ((((c8 >> 1) ^ (erow & 15)) << 4) | ((c8 & 1) << 3));
  const int zrb = erow * 128 + ((((c8 >> 2) ^ (erow & 7)) << 4) | ((c8 & 3) << 2));

  const long stride = gridDim.x;
  long t = blockIdx.x;
  if (t >= NTILES) return;

  f32x4 xr;
  auto gload = [&](long tt) {
    xr = *(const f32x4*)(X + (tt * 16 + rs) * ND + cs * 4);
  };
  auto stage = [&](int bb) {
    bf16x4 b;
#pragma unroll
    for (int i = 0; i < 4; ++i) b[i] = (bf16_t)xr[i];
    *(bf16x4*)((char*)xt[bb] + stb) = b;
  };

  gload(t);
  stage(0);
  {
    const long t1 = t + stride;
    if (t1 < NTILES) gload(t1);
  }
  __syncthreads();
  int b = 0;

  for (; t < NTILES; t += stride) {
    const long tn = t + stride, tn2 = tn + stride;

    bf16x8 xf[4];
#pragma unroll
    for (int kk = 0; kk < 4; ++kk)
      xf[kk] = *(const bf16x8*)((const char*)xt[b] +
               r * 256 + (((kk * 4 + q) ^ (r & 15)) << 4));

    if (tn < NTILES) stage(b ^ 1);
    if (tn2 < NTILES) gload(tn2);

    f32x4 aS = {0.f, 0.f, 0.f, 0.f};
    f32x4 aZ = {0.f, 0.f, 0.f, 0.f};
    f32x4 aT = {0.f, 0.f, 0.f, 0.f};
#pragma unroll
    for (int kk = 0; kk < 4; ++kk) {
      aS = __builtin_amdgcn_mfma_f32_16x16x32_bf16(wiF[kk], xf[kk], aS, 0, 0, 0);
      aZ = __builtin_amdgcn_mfma_f32_16x16x32_bf16(wjF[kk], xf[kk], aZ, 0, 0, 0);
      aT = __builtin_amdgcn_mfma_f32_16x16x32_bf16(uiF[kk], xf[kk], aT, 0, 0, 0);
    }

    bf16x4 pS, pT;
#pragma unroll
    for (int i = 0; i < 4; ++i) {
      pS[i] = (bf16_t)(aS[i] + mbF[i]);
      pT[i] = (bf16_t)(aT[i] + bpF[i]);
    }
    unsigned zpk = 0;
    zpk = __builtin_amdgcn_cvt_pk_fp8_f32(aZ[0], aZ[1], zpk, false);
    zpk = __builtin_amdgcn_cvt_pk_fp8_f32(aZ[2], aZ[3], zpk, true);
    *(bf16x4*)((char*)eS[b] + ewb) = pS;
    *(bf16x4*)((char*)eT[b] + ewb) = pT;
    *(unsigned*)((char*)eZ[b] + ezb) = zpk;

    __syncthreads();   // single barrier per tile

    {
      const long e = t * 16 + erow;
      const bf16x4 vS = *(const bf16x4*)((const char*)eS[b] + erb);
      const bf16x4 vT = *(const bf16x4*)((const char*)eT[b] + erb);
      const unsigned vZ = *(const unsigned*)((const char*)eZ[b] + zrb);
      *(bf16x4*)(Sb + e * ND + c8 * 4) = vS;
      *(bf16x4*)(Tp + t * 4096 + erow * 128 + c8 * 4) = vT;  // packed 4KB/tile
      *(unsigned*)(Zf8 + e * ND + c8 * 4) = vZ;
    }
    b ^= 1;
  }
}

// ---------------------------------------------------------------------------
// k2: hbar[e] = (1/16) * sum_k relu(S[e] + Z[adj[e][k]]), Z in fp8 e4m3.
// r10: 4 edges per wave — quarter-wave per edge, lane covers 8 channels
// (dwordx2 fp8). Halves gather-instruction count vs r7 (one instr fetches
// 4 x 128B rows); S/Hb accesses widen to 16B/lane. Indices distributed
// via __shfl within each 16-lane quarter.
// ---------------------------------------------------------------------------
__global__ __launch_bounds__(256) void k2_gather(
    const u8* __restrict__ Zf8, const u16* __restrict__ Sb,
    const int* __restrict__ adj, u16* __restrict__ Hb)
{
  const int tid = threadIdx.x, w4 = tid >> 6, lane = tid & 63;
  const int q4 = lane >> 4, li = lane & 15;
  const long e = (long)blockIdx.x * 16 + w4 * 4 + q4;
  const int c0 = li * 8;   // channel base (8 fp8 bytes / 8 bf16 u16s)

  const bf16x8 sv = *(const bf16x8*)(Sb + e * ND + c0);
  float s[8];
#pragma unroll
  for (int i = 0; i < 8; ++i) s[i] = (float)sv[i];

  const int myidx = adj[e * NK + li];   // lane li holds neighbor li of its edge

  float acc[8] = {0.f, 0.f, 0.f, 0.f, 0.f, 0.f, 0.f, 0.f};
#pragma unroll
  for (int k = 0; k < NK; ++k) {
    const int n = __shfl(myidx, (lane & 48) + k);
    const u32x2 zw = *(const u32x2*)(Zf8 + (long)n * ND + c0);
    const f32x2 z0 = __builtin_amdgcn_cvt_pk_f32_fp8(zw[0], false);
    const f32x2 z1 = __builtin_amdgcn_cvt_pk_f32_fp8(zw[0], true);
    const f32x2 z2 = __builtin_amdgcn_cvt_pk_f32_fp8(zw[1], false);
    const f32x2 z3 = __builtin_amdgcn_cvt_pk_f32_fp8(zw[1], true);
    acc[0] += fmaxf(s[0] + z0[0], 0.f);
    acc[1] += fmaxf(s[1] + z0[1], 0.f);
    acc[2] += fmaxf(s[2] + z1[0], 0.f);
    acc[3] += fmaxf(s[3] + z1[1], 0.f);
    acc[4] += fmaxf(s[4] + z2[0], 0.f);
    acc[5] += fmaxf(s[5] + z2[1], 0.f);
    acc[6] += fmaxf(s[6] + z3[0], 0.f);
    acc[7] += fmaxf(s[7] + z3[1], 0.f);
  }

  bf16x8 hv;
#pragma unroll
  for (int i = 0; i < 8; ++i) hv[i] = (bf16_t)(acc[i] * 0.0625f);
  *(bf16x8*)(Hb + e * ND + c0) = hv;
}

// ---------------------------------------------------------------------------
// k3: u = relu(T1 + Hb@Wp^T); out = u@uW2^T + ub2. 512 threads / 8 waves;
// wave w owns col-tile w of Wp/W2. Hb AND packed-T1 tiles staged once per
// block into swizzled LDS (coalesced 8B/thread loads); u exchanged via
// swizzled LDS. T1p lives in the first 4 KB of this tile's out region and
// is read (staged) before the out store — same-block ordering via barriers.
// ---------------------------------------------------------------------------
__global__ __launch_bounds__(512) void k3_out(
    const u16* __restrict__ Hb,
    const u16* __restrict__ Wp_b, const u16* __restrict__ W2_b,
    const float* __restrict__ ub2, float* out)
{
  __shared__ u16 ht[16 * ND];
  __shared__ u16 tt[16 * ND];
  __shared__ u16 ut[16 * ND];
  const int tid = threadIdx.x, wid = tid >> 6, lane = tid & 63;
  const int r = lane & 15, q = lane >> 4;
  const u16* tp = (const u16*)out;   // packed T1: 4KB at tile t -> t*4096 u16s

  bf16x8 wpF[4], w2F[4];
  f32x4 ubF;
  {
    const int row = wid * 16 + r;
#pragma unroll
    for (int kk = 0; kk < 4; ++kk) {
      wpF[kk] = *(const bf16x8*)(Wp_b + row * ND + kk * 32 + q * 8);
      w2F[kk] = *(const bf16x8*)(W2_b + row * ND + kk * 32 + q * 8);
    }
    ubF = *(const f32x4*)(ub2 + wid * 16 + q * 4);
  }

  const int rs = tid >> 5, cs = tid & 31;
  const int stb = rs * 256 + ((((cs >> 1) ^ (rs & 15)) << 4) | ((cs & 1) << 3));
  // frag-read byte offset for acc-init from tt (ewb pattern)
  const int trb = r * 256 + ((((wid * 2 + (q >> 1)) ^ (r & 15)) << 4) | ((q & 1) << 3));

  const long stride = gridDim.x;
  long t = blockIdx.x;
  if (t >= NTILES) return;

  bf16x4 hr, tr;
  auto gload = [&](long ttl) {
    hr = *(const bf16x4*)(Hb + (ttl * 16 + rs) * ND + cs * 4);
    tr = *(const bf16x4*)(tp + ttl * 4096 + rs * 128 + cs * 4);
  };
  gload(t);
  *(bf16x4*)((char*)ht + stb) = hr;
  *(bf16x4*)((char*)tt + stb) = tr;
  __syncthreads();

  for (; t < NTILES; t += stride) {
    const long tn = t + stride;
    if (tn < NTILES) gload(tn);

    bf16x8 hf[4];
#pragma unroll
    for (int kk = 0; kk < 4; ++kk)
      hf[kk] = *(const bf16x8*)((const char*)ht +
               r * 256 + (((kk * 4 + q) ^ (r & 15)) << 4));

    f32x4 acc;
    {
      const bf16x4 tv = *(const bf16x4*)((const char*)tt + trb);
#pragma unroll
      for (int i = 0; i < 4; ++i) acc[i] = (float)tv[i];
    }
#pragma unroll
    for (int kk = 0; kk < 4; ++kk)
      acc = __builtin_amdgcn_mfma_f32_16x16x32_bf16(wpF[kk], hf[kk], acc, 0, 0, 0);

    bf16x4 u;
#pragma unroll
    for (int i = 0; i < 4; ++i) u[i] = (bf16_t)fmaxf(acc[i], 0.f);
    const int uwb = r * 256 + ((((wid * 2 + (q >> 1)) ^ (r & 15)) << 4) | ((q & 1) << 3));

    __syncthreads();   // (A) ht/tt/prev-ut reads done
    *(bf16x4*)((char*)ut + uwb) = u;
    if (tn < NTILES) {
      *(bf16x4*)((char*)ht + stb) = hr;
      *(bf16x4*)((char*)tt + stb) = tr;
    }
    __syncthreads();   // (B) ut + next ht/tt visible

    bf16x8 uf[4];
#pragma unroll
    for (int kk = 0; kk < 4; ++kk)
      uf[kk] = *(const bf16x8*)((const char*)ut +
               r * 256 + (((kk * 4 + q) ^ (r & 15)) << 4));

    f32x4 o = {0.f, 0.f, 0.f, 0.f};
#pragma unroll
    for (int kk = 0; kk < 4; ++kk)
      o = __builtin_amdgcn_mfma_f32_16x16x32_bf16(w2F[kk], uf[kk], o, 0, 0, 0);
#pragma unroll
    for (int i = 0; i < 4; ++i) o[i] += ubF[i];
    *(f32x4*)(out + (t * 16 + r) * ND + wid * 16 + q * 4) = o;
  }
}

extern "C" void kernel_launch(void* const* d_in, const int* in_sizes, int n_in,
                              void* d_out, int out_size, void* d_ws, size_t ws_size,
                              hipStream_t stream)
{
  (void)in_sizes; (void)n_in; (void)out_size; (void)ws_size;
  const float* X   = (const float*)d_in[0];
  const int*   adj = (const int*)d_in[1];
  const float* mW1 = (const float*)d_in[2];
  const float* mb1 = (const float*)d_in[3];
  const float* mW2 = (const float*)d_in[4];
  const float* mb2 = (const float*)d_in[5];
  const float* uW1 = (const float*)d_in[6];
  const float* ub1 = (const float*)d_in[7];
  const float* uW2 = (const float*)d_in[8];
  const float* ub2 = (const float*)d_in[9];
  float* out = (float*)d_out;

  u16* ws16 = (u16*)d_ws;
  u16* Sb   = ws16;                              // E*D bf16 (25.6 MB)
  u16* Hb   = Sb + (size_t)NE * ND;              // E*D bf16 (25.6 MB)
  u8*  Zf8  = (u8*)(Hb + (size_t)NE * ND);       // E*D fp8  (12.8 MB)
  u16* Wi_b = (u16*)(Zf8 + (size_t)NE * ND);     // 128*128 bf16 each:
  u16* Wj_b = Wi_b + 128 * 128;
  u16* Ui_b = Wj_b + 128 * 128;
  u16* Wp_b = Ui_b + 128 * 128;
  u16* W2_b = Wp_b + 128 * 128;
  float* bp = (float*)(W2_b + 128 * 128);        // 128 f32
  u16* Tp   = (u16*)d_out;                       // packed T1: 4KB per tile

  k_prep<<<128, 128, 0, stream>>>(mW1, uW1, uW2, mW2, ub1, mb2,
                                  Wi_b, Wj_b, Ui_b, Wp_b, W2_b, bp);

  k1_szt<<<1024, 512, 0, stream>>>(X, Wi_b, Wj_b, Ui_b, mb1, bp, Sb, Zf8, Tp);

  k2_gather<<<NTILES, 256, 0, stream>>>(Zf8, Sb, adj, Hb);

  k3_out<<<1024, 512, 0, stream>>>(Hb, Wp_b, W2_b, ub2, out);
}

// Round 11
// 95.030 us; speedup vs baseline: 1.0279x; 1.0021x over previous
//
#include <hip/hip_runtime.h>
#include <hip/hip_bf16.h>

#define NE 100000
#define NK 16
#define ND 128
#define NTILES 6250   // NE / 16

typedef __bf16 bf16_t;
typedef bf16_t bf16x8 __attribute__((ext_vector_type(8)));
typedef bf16_t bf16x4 __attribute__((ext_vector_type(4)));
typedef float f32x4 __attribute__((ext_vector_type(4)));
typedef float f32x2 __attribute__((ext_vector_type(2)));
typedef unsigned u32x2 __attribute__((ext_vector_type(2)));
typedef unsigned short u16;
typedef unsigned char u8;

__device__ __forceinline__ u16 f2bf(float f) {
  bf16_t h = (bf16_t)f;
  return __builtin_bit_cast(u16, h);
}

// ---------------------------------------------------------------------------
// k_prep: bf16-convert weights; fold Wp = Um@mW2, bp = ub1 + Um@mb2.
// ---------------------------------------------------------------------------
__global__ void k_prep(const float* __restrict__ mW1, const float* __restrict__ uW1,
                       const float* __restrict__ uW2, const float* __restrict__ mW2,
                       const float* __restrict__ ub1, const float* __restrict__ mb2,
                       u16* __restrict__ Wi_b, u16* __restrict__ Wj_b,
                       u16* __restrict__ Ui_b, u16* __restrict__ Wp_b,
                       u16* __restrict__ W2_b, float* __restrict__ bp)
{
  const int o = blockIdx.x, t = threadIdx.x;
  Wi_b[o * ND + t] = f2bf(mW1[o * 256 + t]);
  Wj_b[o * ND + t] = f2bf(mW1[o * 256 + 128 + t]);
  Ui_b[o * ND + t] = f2bf(uW1[o * 256 + t]);
  W2_b[o * ND + t] = f2bf(uW2[o * ND + t]);
  float acc = 0.f;
  for (int p = 0; p < 128; ++p)
    acc += uW1[o * 256 + 128 + p] * mW2[p * 128 + t];
  Wp_b[o * ND + t] = f2bf(acc);
  if (t == 0) {
    float b = ub1[o];
    for (int p = 0; p < 128; ++p) b += uW1[o * 256 + 128 + p] * mb2[p];
    bp[o] = b;
  }
}

// ---------------------------------------------------------------------------
// k1: S = X@Wi^T + mb1 (fp8 e4m3), Z = X@Wj^T (fp8 e4m3), T1 = X@Ui^T + bp
// (bf16, packed 4 KB/tile into out). r11: S now fp8 like Z (halves k2's
// S-stream). Structure otherwise r9/r10: 512 thr / 8 waves, wave w owns
// col-tile w, double-buffered X tile + epilogue tiles, one barrier/tile.
// ---------------------------------------------------------------------------
__global__ __launch_bounds__(512) void k1_szt(
    const float* __restrict__ X, const u16* __restrict__ Wi_b,
    const u16* __restrict__ Wj_b, const u16* __restrict__ Ui_b,
    const float* __restrict__ mb1, const float* __restrict__ bp,
    u8* __restrict__ Sf8, u8* __restrict__ Zf8, u16* __restrict__ Tp)
{
  __shared__ u16 xt[2][16 * ND];   // 2 x 4 KB X tile (bf16, swizzled)
  __shared__ u8  eS[2][16 * ND];   // 2 x 2 KB epilogue S (fp8)
  __shared__ u8  eZ[2][16 * ND];   // 2 x 2 KB epilogue Z (fp8)
  __shared__ u16 eT[2][16 * ND];   // 2 x 4 KB epilogue T1
  const int tid = threadIdx.x, wid = tid >> 6, lane = tid & 63;
  const int r = lane & 15, q = lane >> 4;

  bf16x8 wiF[4], wjF[4], uiF[4];
  f32x4 mbF, bpF;
  {
    const int row = wid * 16 + r;
#pragma unroll
    for (int kk = 0; kk < 4; ++kk) {
      wiF[kk] = *(const bf16x8*)(Wi_b + row * ND + kk * 32 + q * 8);
      wjF[kk] = *(const bf16x8*)(Wj_b + row * ND + kk * 32 + q * 8);
      uiF[kk] = *(const bf16x8*)(Ui_b + row * ND + kk * 32 + q * 8);
    }
    mbF = *(const f32x4*)(mb1 + wid * 16 + q * 4);
    bpF = *(const f32x4*)(bp  + wid * 16 + q * 4);
  }

  const int rs = tid >> 5, cs = tid & 31;
  const int stb = rs * 256 + ((((cs >> 1) ^ (rs & 15)) << 4) | ((cs & 1) << 3));
  const int ewb = r * 256 + ((((wid * 2 + (q >> 1)) ^ (r & 15)) << 4) | ((q & 1) << 3));
  const int ezb = r * 128 + (((wid ^ (r & 7)) << 4) | (q * 4));
  const int erow = tid >> 5, c8 = tid & 31;
  const int erb = erow * 256 + ((((c8 >> 1) ^ (erow & 15)) << 4) | ((c8 & 1) << 3));
  const int zrb = erow * 128 + ((((c8 >> 2) ^ (erow & 7)) << 4) | ((c8 & 3) << 2));

  const long stride = gridDim.x;
  long t = blockIdx.x;
  if (t >= NTILES) return;

  f32x4 xr;
  auto gload = [&](long tt) {
    xr = *(const f32x4*)(X + (tt * 16 + rs) * ND + cs * 4);
  };
  auto stage = [&](int bb) {
    bf16x4 b;
#pragma unroll
    for (int i = 0; i < 4; ++i) b[i] = (bf16_t)xr[i];
    *(bf16x4*)((char*)xt[bb] + stb) = b;
  };

  gload(t);
  stage(0);
  {
    const long t1 = t + stride;
    if (t1 < NTILES) gload(t1);
  }
  __syncthreads();
  int b = 0;

  for (; t < NTILES; t += stride) {
    const long tn = t + stride, tn2 = tn + stride;

    bf16x8 xf[4];
#pragma unroll
    for (int kk = 0; kk < 4; ++kk)
      xf[kk] = *(const bf16x8*)((const char*)xt[b] +
               r * 256 + (((kk * 4 + q) ^ (r & 15)) << 4));

    if (tn < NTILES) stage(b ^ 1);
    if (tn2 < NTILES) gload(tn2);

    f32x4 aS = {0.f, 0.f, 0.f, 0.f};
    f32x4 aZ = {0.f, 0.f, 0.f, 0.f};
    f32x4 aT = {0.f, 0.f, 0.f, 0.f};
#pragma unroll
    for (int kk = 0; kk < 4; ++kk) {
      aS = __builtin_amdgcn_mfma_f32_16x16x32_bf16(wiF[kk], xf[kk], aS, 0, 0, 0);
      aZ = __builtin_amdgcn_mfma_f32_16x16x32_bf16(wjF[kk], xf[kk], aZ, 0, 0, 0);
      aT = __builtin_amdgcn_mfma_f32_16x16x32_bf16(uiF[kk], xf[kk], aT, 0, 0, 0);
    }

    bf16x4 pT;
#pragma unroll
    for (int i = 0; i < 4; ++i) pT[i] = (bf16_t)(aT[i] + bpF[i]);
    unsigned spk = 0, zpk = 0;
    spk = __builtin_amdgcn_cvt_pk_fp8_f32(aS[0] + mbF[0], aS[1] + mbF[1], spk, false);
    spk = __builtin_amdgcn_cvt_pk_fp8_f32(aS[2] + mbF[2], aS[3] + mbF[3], spk, true);
    zpk = __builtin_amdgcn_cvt_pk_fp8_f32(aZ[0], aZ[1], zpk, false);
    zpk = __builtin_amdgcn_cvt_pk_fp8_f32(aZ[2], aZ[3], zpk, true);
    *(unsigned*)((char*)eS[b] + ezb) = spk;
    *(unsigned*)((char*)eZ[b] + ezb) = zpk;
    *(bf16x4*)((char*)eT[b] + ewb) = pT;

    __syncthreads();   // single barrier per tile

    {
      const long e = t * 16 + erow;
      const unsigned vS = *(const unsigned*)((const char*)eS[b] + zrb);
      const unsigned vZ = *(const unsigned*)((const char*)eZ[b] + zrb);
      const bf16x4 vT = *(const bf16x4*)((const char*)eT[b] + erb);
      *(unsigned*)(Sf8 + e * ND + c8 * 4) = vS;
      *(unsigned*)(Zf8 + e * ND + c8 * 4) = vZ;
      *(bf16x4*)(Tp + t * 4096 + erow * 128 + c8 * 4) = vT;
    }
    b ^= 1;
  }
}

// ---------------------------------------------------------------------------
// k2: hbar[e] = (1/16) * sum_k relu(S[e] + Z[adj[e][k]]), S/Z/H all fp8.
// 4 edges/wave, quarter-wave per edge, dwordx2 gathers (r10 structure).
// r11: S/adj loads and H stores are NON-TEMPORAL — the streams no longer
// evict Z lines from the 4 MB/XCD L2, protecting gather hit-rate.
// ---------------------------------------------------------------------------
__global__ __launch_bounds__(256) void k2_gather(
    const u8* __restrict__ Zf8, const u8* __restrict__ Sf8,
    const int* __restrict__ adj, u8* __restrict__ Hf8)
{
  const int tid = threadIdx.x, w4 = tid >> 6, lane = tid & 63;
  const int q4 = lane >> 4, li = lane & 15;
  const long e = (long)blockIdx.x * 16 + w4 * 4 + q4;
  const int c0 = li * 8;   // fp8 byte base = channel base

  const unsigned* sp = (const unsigned*)(Sf8 + e * ND + c0);
  const unsigned sw0 = __builtin_nontemporal_load(sp);
  const unsigned sw1 = __builtin_nontemporal_load(sp + 1);
  const f32x2 s0 = __builtin_amdgcn_cvt_pk_f32_fp8(sw0, false);
  const f32x2 s1 = __builtin_amdgcn_cvt_pk_f32_fp8(sw0, true);
  const f32x2 s2 = __builtin_amdgcn_cvt_pk_f32_fp8(sw1, false);
  const f32x2 s3 = __builtin_amdgcn_cvt_pk_f32_fp8(sw1, true);
  const float s[8] = {s0[0], s0[1], s1[0], s1[1], s2[0], s2[1], s3[0], s3[1]};

  const int myidx = __builtin_nontemporal_load(adj + e * NK + li);

  float acc[8] = {0.f, 0.f, 0.f, 0.f, 0.f, 0.f, 0.f, 0.f};
#pragma unroll
  for (int k = 0; k < NK; ++k) {
    const int n = __shfl(myidx, (lane & 48) + k);
    const u32x2 zw = *(const u32x2*)(Zf8 + (long)n * ND + c0);
    const f32x2 z0 = __builtin_amdgcn_cvt_pk_f32_fp8(zw[0], false);
    const f32x2 z1 = __builtin_amdgcn_cvt_pk_f32_fp8(zw[0], true);
    const f32x2 z2 = __builtin_amdgcn_cvt_pk_f32_fp8(zw[1], false);
    const f32x2 z3 = __builtin_amdgcn_cvt_pk_f32_fp8(zw[1], true);
    acc[0] += fmaxf(s[0] + z0[0], 0.f);
    acc[1] += fmaxf(s[1] + z0[1], 0.f);
    acc[2] += fmaxf(s[2] + z1[0], 0.f);
    acc[3] += fmaxf(s[3] + z1[1], 0.f);
    acc[4] += fmaxf(s[4] + z2[0], 0.f);
    acc[5] += fmaxf(s[5] + z2[1], 0.f);
    acc[6] += fmaxf(s[6] + z3[0], 0.f);
    acc[7] += fmaxf(s[7] + z3[1], 0.f);
  }

  unsigned h0 = 0, h1 = 0;
  h0 = __builtin_amdgcn_cvt_pk_fp8_f32(acc[0] * 0.0625f, acc[1] * 0.0625f, h0, false);
  h0 = __builtin_amdgcn_cvt_pk_fp8_f32(acc[2] * 0.0625f, acc[3] * 0.0625f, h0, true);
  h1 = __builtin_amdgcn_cvt_pk_fp8_f32(acc[4] * 0.0625f, acc[5] * 0.0625f, h1, false);
  h1 = __builtin_amdgcn_cvt_pk_fp8_f32(acc[6] * 0.0625f, acc[7] * 0.0625f, h1, true);
  unsigned* hp = (unsigned*)(Hf8 + e * ND + c0);
  __builtin_nontemporal_store(h0, hp);
  __builtin_nontemporal_store(h1, hp + 1);
}

// ---------------------------------------------------------------------------
// k3: u = relu(T1 + hbar@Wp^T); out = u@uW2^T + ub2. Hbar now fp8: staged
// thread-dword loads convert to bf16 on the LDS write. Otherwise r10.
// ---------------------------------------------------------------------------
__global__ __launch_bounds__(512) void k3_out(
    const u8* __restrict__ Hf8,
    const u16* __restrict__ Wp_b, const u16* __restrict__ W2_b,
    const float* __restrict__ ub2, float* out)
{
  __shared__ u16 ht[16 * ND];
  __shared__ u16 tt[16 * ND];
  __shared__ u16 ut[16 * ND];
  const int tid = threadIdx.x, wid = tid >> 6, lane = tid & 63;
  const int r = lane & 15, q = lane >> 4;
  const u16* tp = (const u16*)out;   // packed T1: 4 KB at tile t

  bf16x8 wpF[4], w2F[4];
  f32x4 ubF;
  {
    const int row = wid * 16 + r;
#pragma unroll
    for (int kk = 0; kk < 4; ++kk) {
      wpF[kk] = *(const bf16x8*)(Wp_b + row * ND + kk * 32 + q * 8);
      w2F[kk] = *(const bf16x8*)(W2_b + row * ND + kk * 32 + q * 8);
    }
    ubF = *(const f32x4*)(ub2 + wid * 16 + q * 4);
  }

  const int rs = tid >> 5, cs = tid & 31;
  const int stb = rs * 256 + ((((cs >> 1) ^ (rs & 15)) << 4) | ((cs & 1) << 3));
  const int trb = r * 256 + ((((wid * 2 + (q >> 1)) ^ (r & 15)) << 4) | ((q & 1) << 3));

  const long stride = gridDim.x;
  long t = blockIdx.x;
  if (t >= NTILES) return;

  unsigned hw;
  bf16x4 tr;
  auto gload = [&](long ttl) {
    hw = *(const unsigned*)(Hf8 + (ttl * 16 + rs) * ND + cs * 4);
    tr = *(const bf16x4*)(tp + ttl * 4096 + rs * 128 + cs * 4);
  };
  auto stageh = [&]() {
    const f32x2 lo = __builtin_amdgcn_cvt_pk_f32_fp8(hw, false);
    const f32x2 hi = __builtin_amdgcn_cvt_pk_f32_fp8(hw, true);
    bf16x4 hb;
    hb[0] = (bf16_t)lo[0]; hb[1] = (bf16_t)lo[1];
    hb[2] = (bf16_t)hi[0]; hb[3] = (bf16_t)hi[1];
    *(bf16x4*)((char*)ht + stb) = hb;
  };
  gload(t);
  stageh();
  *(bf16x4*)((char*)tt + stb) = tr;
  __syncthreads();

  for (; t < NTILES; t += stride) {
    const long tn = t + stride;
    if (tn < NTILES) gload(tn);

    bf16x8 hf[4];
#pragma unroll
    for (int kk = 0; kk < 4; ++kk)
      hf[kk] = *(const bf16x8*)((const char*)ht +
               r * 256 + (((kk * 4 + q) ^ (r & 15)) << 4));

    f32x4 acc;
    {
      const bf16x4 tv = *(const bf16x4*)((const char*)tt + trb);
#pragma unroll
      for (int i = 0; i < 4; ++i) acc[i] = (float)tv[i];
    }
#pragma unroll
    for (int kk = 0; kk < 4; ++kk)
      acc = __builtin_amdgcn_mfma_f32_16x16x32_bf16(wpF[kk], hf[kk], acc, 0, 0, 0);

    bf16x4 u;
#pragma unroll
    for (int i = 0; i < 4; ++i) u[i] = (bf16_t)fmaxf(acc[i], 0.f);
    const int uwb = r * 256 + ((((wid * 2 + (q >> 1)) ^ (r & 15)) << 4) | ((q & 1) << 3));

    __syncthreads();   // (A) ht/tt/prev-ut reads done
    *(bf16x4*)((char*)ut + uwb) = u;
    if (tn < NTILES) {
      stageh();
      *(bf16x4*)((char*)tt + stb) = tr;
    }
    __syncthreads();   // (B) ut + next ht/tt visible

    bf16x8 uf[4];
#pragma unroll
    for (int kk = 0; kk < 4; ++kk)
      uf[kk] = *(const bf16x8*)((const char*)ut +
               r * 256 + (((kk * 4 + q) ^ (r & 15)) << 4));

    f32x4 o = {0.f, 0.f, 0.f, 0.f};
#pragma unroll
    for (int kk = 0; kk < 4; ++kk)
      o = __builtin_amdgcn_mfma_f32_16x16x32_bf16(w2F[kk], uf[kk], o, 0, 0, 0);
#pragma unroll
    for (int i = 0; i < 4; ++i) o[i] += ubF[i];
    *(f32x4*)(out + (t * 16 + r) * ND + wid * 16 + q * 4) = o;
  }
}

extern "C" void kernel_launch(void* const* d_in, const int* in_sizes, int n_in,
                              void* d_out, int out_size, void* d_ws, size_t ws_size,
                              hipStream_t stream)
{
  (void)in_sizes; (void)n_in; (void)out_size; (void)ws_size;
  const float* X   = (const float*)d_in[0];
  const int*   adj = (const int*)d_in[1];
  const float* mW1 = (const float*)d_in[2];
  const float* mb1 = (const float*)d_in[3];
  const float* mW2 = (const float*)d_in[4];
  const float* mb2 = (const float*)d_in[5];
  const float* uW1 = (const float*)d_in[6];
  const float* ub1 = (const float*)d_in[7];
  const float* uW2 = (const float*)d_in[8];
  const float* ub2 = (const float*)d_in[9];
  float* out = (float*)d_out;

  u8* ws8  = (u8*)d_ws;
  u8* Sf8  = ws8;                                // E*ND fp8 (12.8 MB)
  u8* Hf8  = Sf8 + (size_t)NE * ND;              // E*ND fp8 (12.8 MB)
  u8* Zf8  = Hf8 + (size_t)NE * ND;              // E*ND fp8 (12.8 MB)
  u16* Wi_b = (u16*)(Zf8 + (size_t)NE * ND);     // 128*128 bf16 each:
  u16* Wj_b = Wi_b + 128 * 128;
  u16* Ui_b = Wj_b + 128 * 128;
  u16* Wp_b = Ui_b + 128 * 128;
  u16* W2_b = Wp_b + 128 * 128;
  float* bp = (float*)(W2_b + 128 * 128);        // 128 f32
  u16* Tp   = (u16*)d_out;                       // packed T1: 4 KB per tile

  k_prep<<<128, 128, 0, stream>>>(mW1, uW1, uW2, mW2, ub1, mb2,
                                  Wi_b, Wj_b, Ui_b, Wp_b, W2_b, bp);

  k1_szt<<<1024, 512, 0, stream>>>(X, Wi_b, Wj_b, Ui_b, mb1, bp, Sf8, Zf8, Tp);

  k2_gather<<<NTILES, 256, 0, stream>>>(Zf8, Sf8, adj, Hf8);

  k3_out<<<1024, 512, 0, stream>>>(Hf8, Wp_b, W2_b, ub2, out);
}

// Round 13
// 87.537 us; speedup vs baseline: 1.1158x; 1.0856x over previous
//
#include <hip/hip_runtime.h>
#include <hip/hip_bf16.h>

#define NE 100000
#define NK 16
#define ND 128
#define NTILES 6250   // NE / 16
#define NSUP 3125     // NE / 32

typedef __bf16 bf16_t;
typedef bf16_t bf16x8 __attribute__((ext_vector_type(8)));
typedef bf16_t bf16x4 __attribute__((ext_vector_type(4)));
typedef float f32x4 __attribute__((ext_vector_type(4)));
typedef float f32x2 __attribute__((ext_vector_type(2)));
typedef unsigned u32x2 __attribute__((ext_vector_type(2)));
typedef unsigned short u16;
typedef unsigned char u8;

__device__ __forceinline__ u16 f2bf(float f) {
  bf16_t h = (bf16_t)f;
  return __builtin_bit_cast(u16, h);
}

// lgkmcnt-only barrier: LDS writes are made visible, but in-flight GLOBAL
// loads/stores ride across (no vmcnt(0) drain -> prefetches survive).
__device__ __forceinline__ void soft_barrier() {
  asm volatile("s_waitcnt lgkmcnt(0)" ::: "memory");
  __builtin_amdgcn_s_barrier();
}

// ---------------------------------------------------------------------------
// k_prep: bf16-convert weights; fold Wp = Um@mW2, bp = ub1 + Um@mb2.
// ---------------------------------------------------------------------------
__global__ void k_prep(const float* __restrict__ mW1, const float* __restrict__ uW1,
                       const float* __restrict__ uW2, const float* __restrict__ mW2,
                       const float* __restrict__ ub1, const float* __restrict__ mb2,
                       u16* __restrict__ Wi_b, u16* __restrict__ Wj_b,
                       u16* __restrict__ Ui_b, u16* __restrict__ Wp_b,
                       u16* __restrict__ W2_b, float* __restrict__ bp)
{
  const int o = blockIdx.x, t = threadIdx.x;
  Wi_b[o * ND + t] = f2bf(mW1[o * 256 + t]);
  Wj_b[o * ND + t] = f2bf(mW1[o * 256 + 128 + t]);
  Ui_b[o * ND + t] = f2bf(uW1[o * 256 + t]);
  W2_b[o * ND + t] = f2bf(uW2[o * ND + t]);
  float acc = 0.f;
  for (int p = 0; p < 128; ++p)
    acc += uW1[o * 256 + 128 + p] * mW2[p * 128 + t];
  Wp_b[o * ND + t] = f2bf(acc);
  if (t == 0) {
    float b = ub1[o];
    for (int p = 0; p < 128; ++p) b += uW1[o * 256 + 128 + p] * mb2[p];
    bp[o] = b;
  }
}

// ---------------------------------------------------------------------------
// k1: S = X@Wi^T + mb1 (fp8), Z = X@Wj^T (fp8), T1 = X@Ui^T + bp (bf16,
// TIGHT-packed 2048 u16 per 16-edge tile in ws — r12 bug was stride 4096,
// overflowing 2x into the weight tables). lgkm-only barrier per tile keeps
// the 2-deep X prefetch alive.
// ---------------------------------------------------------------------------
__global__ __launch_bounds__(512) void k1_szt(
    const float* __restrict__ X, const u16* __restrict__ Wi_b,
    const u16* __restrict__ Wj_b, const u16* __restrict__ Ui_b,
    const float* __restrict__ mb1, const float* __restrict__ bp,
    u8* __restrict__ Sf8, u8* __restrict__ Zf8, u16* __restrict__ Tp)
{
  __shared__ u16 xt[2][16 * ND];
  __shared__ u8  eS[2][16 * ND];
  __shared__ u8  eZ[2][16 * ND];
  __shared__ u16 eT[2][16 * ND];
  const int tid = threadIdx.x, wid = tid >> 6, lane = tid & 63;
  const int r = lane & 15, q = lane >> 4;

  bf16x8 wiF[4], wjF[4], uiF[4];
  f32x4 mbF, bpF;
  {
    const int row = wid * 16 + r;
#pragma unroll
    for (int kk = 0; kk < 4; ++kk) {
      wiF[kk] = *(const bf16x8*)(Wi_b + row * ND + kk * 32 + q * 8);
      wjF[kk] = *(const bf16x8*)(Wj_b + row * ND + kk * 32 + q * 8);
      uiF[kk] = *(const bf16x8*)(Ui_b + row * ND + kk * 32 + q * 8);
    }
    mbF = *(const f32x4*)(mb1 + wid * 16 + q * 4);
    bpF = *(const f32x4*)(bp  + wid * 16 + q * 4);
  }

  const int rs = tid >> 5, cs = tid & 31;
  const int stb = rs * 256 + ((((cs >> 1) ^ (rs & 15)) << 4) | ((cs & 1) << 3));
  const int ewb = r * 256 + ((((wid * 2 + (q >> 1)) ^ (r & 15)) << 4) | ((q & 1) << 3));
  const int ezb = r * 128 + (((wid ^ (r & 7)) << 4) | (q * 4));
  const int erow = tid >> 5, c8 = tid & 31;
  const int erb = erow * 256 + ((((c8 >> 1) ^ (erow & 15)) << 4) | ((c8 & 1) << 3));
  const int zrb = erow * 128 + ((((c8 >> 2) ^ (erow & 7)) << 4) | ((c8 & 3) << 2));

  const long stride = gridDim.x;
  long t = blockIdx.x;
  if (t >= NTILES) return;

  f32x4 xr;
  auto gload = [&](long tt) {
    xr = *(const f32x4*)(X + (tt * 16 + rs) * ND + cs * 4);
  };
  auto stage = [&](int bb) {
    bf16x4 b;
#pragma unroll
    for (int i = 0; i < 4; ++i) b[i] = (bf16_t)xr[i];
    *(bf16x4*)((char*)xt[bb] + stb) = b;
  };

  gload(t);
  stage(0);
  {
    const long t1 = t + stride;
    if (t1 < NTILES) gload(t1);
  }
  soft_barrier();
  int b = 0;

  for (; t < NTILES; t += stride) {
    const long tn = t + stride, tn2 = tn + stride;

    bf16x8 xf[4];
#pragma unroll
    for (int kk = 0; kk < 4; ++kk)
      xf[kk] = *(const bf16x8*)((const char*)xt[b] +
               r * 256 + (((kk * 4 + q) ^ (r & 15)) << 4));

    if (tn < NTILES) stage(b ^ 1);
    if (tn2 < NTILES) gload(tn2);

    f32x4 aS = {0.f, 0.f, 0.f, 0.f};
    f32x4 aZ = {0.f, 0.f, 0.f, 0.f};
    f32x4 aT = {0.f, 0.f, 0.f, 0.f};
#pragma unroll
    for (int kk = 0; kk < 4; ++kk) {
      aS = __builtin_amdgcn_mfma_f32_16x16x32_bf16(wiF[kk], xf[kk], aS, 0, 0, 0);
      aZ = __builtin_amdgcn_mfma_f32_16x16x32_bf16(wjF[kk], xf[kk], aZ, 0, 0, 0);
      aT = __builtin_amdgcn_mfma_f32_16x16x32_bf16(uiF[kk], xf[kk], aT, 0, 0, 0);
    }

    bf16x4 pT;
#pragma unroll
    for (int i = 0; i < 4; ++i) pT[i] = (bf16_t)(aT[i] + bpF[i]);
    unsigned spk = 0, zpk = 0;
    spk = __builtin_amdgcn_cvt_pk_fp8_f32(aS[0] + mbF[0], aS[1] + mbF[1], spk, false);
    spk = __builtin_amdgcn_cvt_pk_fp8_f32(aS[2] + mbF[2], aS[3] + mbF[3], spk, true);
    zpk = __builtin_amdgcn_cvt_pk_fp8_f32(aZ[0], aZ[1], zpk, false);
    zpk = __builtin_amdgcn_cvt_pk_fp8_f32(aZ[2], aZ[3], zpk, true);
    *(unsigned*)((char*)eS[b] + ezb) = spk;
    *(unsigned*)((char*)eZ[b] + ezb) = zpk;
    *(bf16x4*)((char*)eT[b] + ewb) = pT;

    soft_barrier();   // single lgkm-only barrier per tile

    {
      const long e = t * 16 + erow;
      const unsigned vS = *(const unsigned*)((const char*)eS[b] + zrb);
      const unsigned vZ = *(const unsigned*)((const char*)eZ[b] + zrb);
      const bf16x4 vT = *(const bf16x4*)((const char*)eT[b] + erb);
      *(unsigned*)(Sf8 + e * ND + c8 * 4) = vS;
      *(unsigned*)(Zf8 + e * ND + c8 * 4) = vZ;
      *(bf16x4*)(Tp + t * 2048 + erow * 128 + c8 * 4) = vT;   // tight pack
    }
    b ^= 1;
  }
}

// ---------------------------------------------------------------------------
// k23: FUSED gather + both update GEMMs. Block = 512 thr / 8 waves handles a
// 32-edge supertile (2 GEMM sub-tiles) per grid-stride iteration.
// Gather: wave w owns edges {4w..4w+3} via quarter-waves (lane r covers 8
// channels, dwordx2 fp8 loads); H accumulated IN REGISTERS. The NEXT
// supertile's 16 Z-gathers are issued in two 8-load bursts and ride across
// lgkm-only barriers, hiding under the current supertile's 32 MFMAs.
// H never touches global memory. Wp/W2 register-resident.
// ---------------------------------------------------------------------------
__global__ __launch_bounds__(512) void k23_fused(
    const u8* __restrict__ Zf8, const u8* __restrict__ Sf8,
    const int* __restrict__ adj, const u16* __restrict__ Tp,
    const u16* __restrict__ Wp_b, const u16* __restrict__ W2_b,
    const float* __restrict__ ub2, float* __restrict__ out)
{
  __shared__ u16 ht[32 * ND];   // 8 KB  hbar (bf16, swizzled)
  __shared__ u16 tt[32 * ND];   // 8 KB  T1
  __shared__ u16 ut[32 * ND];   // 8 KB  u exchange
  const int tid = threadIdx.x, wid = tid >> 6, lane = tid & 63;
  const int r = lane & 15, q = lane >> 4;
  const int ew = wid * 4 + q;          // edge-in-supertile (gather/H rows)
  const int c0 = r * 8;                // gather channel base (8 fp8 bytes)

  bf16x8 wpF[4], w2F[4];
  f32x4 ubF;
  {
    const int row = wid * 16 + r;
#pragma unroll
    for (int kk = 0; kk < 4; ++kk) {
      wpF[kk] = *(const bf16x8*)(Wp_b + row * ND + kk * 32 + q * 8);
      w2F[kk] = *(const bf16x8*)(W2_b + row * ND + kk * 32 + q * 8);
    }
    ubF = *(const f32x4*)(ub2 + wid * 16 + q * 4);
  }

  // LDS byte offsets
  const int hwb = ew * 256 + ((r ^ (ew & 15)) << 4);          // ht write 16B
  const int trow = tid >> 4, tch = tid & 15;                  // tt stage
  const int twb = trow * 256 + ((tch ^ (trow & 15)) << 4);    // tt write 16B
  const int uwb0 = (((wid * 2 + (q >> 1)) ^ r) << 4) | ((q & 1) << 3);

  const long stride = gridDim.x;
  long s = blockIdx.x;
  if (s >= NSUP) return;

  auto adjload = [&](long ss) { return adj[(ss * 32 + ew) * NK + r]; };

  // ---- prologue: gather-accumulate supertile s serially ----
  int myidxN;   // adj row for s+stride (prefetched)
  float hacc[8];
  bf16x8 trC;
  {
    const int myidxC = adjload(s);
    const unsigned* sp = (const unsigned*)(Sf8 + (s * 32 + ew) * ND + c0);
    const unsigned sw0 = sp[0], sw1 = sp[1];
    trC = *(const bf16x8*)(Tp + s * 4096 + trow * 128 + tch * 8);
    const long s1 = s + stride;
    myidxN = (s1 < NSUP) ? adjload(s1) : 0;

    const f32x2 a0 = __builtin_amdgcn_cvt_pk_f32_fp8(sw0, false);
    const f32x2 a1 = __builtin_amdgcn_cvt_pk_f32_fp8(sw0, true);
    const f32x2 a2 = __builtin_amdgcn_cvt_pk_f32_fp8(sw1, false);
    const f32x2 a3 = __builtin_amdgcn_cvt_pk_f32_fp8(sw1, true);
    const float sv[8] = {a0[0], a0[1], a1[0], a1[1], a2[0], a2[1], a3[0], a3[1]};
#pragma unroll
    for (int i = 0; i < 8; ++i) hacc[i] = 0.f;
#pragma unroll
    for (int k = 0; k < NK; ++k) {
      const int n = __shfl(myidxC, (lane & 48) + k);
      const u32x2 zw = *(const u32x2*)(Zf8 + (long)n * ND + c0);
      const f32x2 z0 = __builtin_amdgcn_cvt_pk_f32_fp8(zw[0], false);
      const f32x2 z1 = __builtin_amdgcn_cvt_pk_f32_fp8(zw[0], true);
      const f32x2 z2 = __builtin_amdgcn_cvt_pk_f32_fp8(zw[1], false);
      const f32x2 z3 = __builtin_amdgcn_cvt_pk_f32_fp8(zw[1], true);
      hacc[0] += fmaxf(sv[0] + z0[0], 0.f);
      hacc[1] += fmaxf(sv[1] + z0[1], 0.f);
      hacc[2] += fmaxf(sv[2] + z1[0], 0.f);
      hacc[3] += fmaxf(sv[3] + z1[1], 0.f);
      hacc[4] += fmaxf(sv[4] + z2[0], 0.f);
      hacc[5] += fmaxf(sv[5] + z2[1], 0.f);
      hacc[6] += fmaxf(sv[6] + z3[0], 0.f);
      hacc[7] += fmaxf(sv[7] + z3[1], 0.f);
    }
  }

  for (; s < NSUP; s += stride) {
    const long sn = s + stride, sn2 = sn + stride;
    const bool hasN = (sn < NSUP);

    // ---- A-store: hbar -> ht, T1 -> tt ----
    {
      bf16x8 hv;
#pragma unroll
      for (int i = 0; i < 8; ++i) hv[i] = (bf16_t)(hacc[i] * 0.0625f);
      *(bf16x8*)((char*)ht + hwb) = hv;
      *(bf16x8*)((char*)tt + twb) = trC;
    }

    // ---- prefetch burst A for sn: 8 Z-gathers + S + Tp + adj(sn2) ----
    u32x2 zbufA[8], zbufB[8];
    unsigned swn0 = 0, swn1 = 0;
    bf16x8 trN = {};
    int myidxN2 = 0;
    if (hasN) {
#pragma unroll
      for (int k = 0; k < 8; ++k) {
        const int n = __shfl(myidxN, (lane & 48) + k);
        zbufA[k] = *(const u32x2*)(Zf8 + (long)n * ND + c0);
      }
      const unsigned* sp = (const unsigned*)(Sf8 + (sn * 32 + ew) * ND + c0);
      swn0 = sp[0]; swn1 = sp[1];
      trN = *(const bf16x8*)(Tp + sn * 4096 + trow * 128 + tch * 8);
      if (sn2 < NSUP) myidxN2 = adjload(sn2);
    }

    soft_barrier();   // ht/tt visible; prefetch loads ride across

    // ---- phase B1: u = relu(T1 + hbar@Wp^T) for both sub-tiles ----
#pragma unroll
    for (int t2 = 0; t2 < 2; ++t2) {
      const int rowb = (t2 * 16 + r) * 256;
      bf16x8 hf[4];
#pragma unroll
      for (int kk = 0; kk < 4; ++kk)
        hf[kk] = *(const bf16x8*)((const char*)ht + rowb + (((kk * 4 + q) ^ r) << 4));
      f32x4 acc;
      {
        const bf16x4 tv = *(const bf16x4*)((const char*)tt + rowb + uwb0);
#pragma unroll
        for (int i = 0; i < 4; ++i) acc[i] = (float)tv[i];
      }
#pragma unroll
      for (int kk = 0; kk < 4; ++kk)
        acc = __builtin_amdgcn_mfma_f32_16x16x32_bf16(wpF[kk], hf[kk], acc, 0, 0, 0);
      bf16x4 u;
#pragma unroll
      for (int i = 0; i < 4; ++i) u[i] = (bf16_t)fmaxf(acc[i], 0.f);
      *(bf16x4*)((char*)ut + rowb + uwb0) = u;
    }

    // ---- prefetch burst B for sn: remaining 8 Z-gathers ----
    if (hasN) {
#pragma unroll
      for (int k = 0; k < 8; ++k) {
        const int n = __shfl(myidxN, (lane & 48) + 8 + k);
        zbufB[k] = *(const u32x2*)(Zf8 + (long)n * ND + c0);
      }
    }

    soft_barrier();   // ut visible

    // ---- phase B2: out = u@uW2^T + ub2 ----
#pragma unroll
    for (int t2 = 0; t2 < 2; ++t2) {
      const int rowb = (t2 * 16 + r) * 256;
      bf16x8 uf[4];
#pragma unroll
      for (int kk = 0; kk < 4; ++kk)
        uf[kk] = *(const bf16x8*)((const char*)ut + rowb + (((kk * 4 + q) ^ r) << 4));
      f32x4 o = {0.f, 0.f, 0.f, 0.f};
#pragma unroll
      for (int kk = 0; kk < 4; ++kk)
        o = __builtin_amdgcn_mfma_f32_16x16x32_bf16(w2F[kk], uf[kk], o, 0, 0, 0);
#pragma unroll
      for (int i = 0; i < 4; ++i) o[i] += ubF[i];
      *(f32x4*)(out + (s * 32 + t2 * 16 + r) * ND + wid * 16 + q * 4) = o;
    }

    // ---- consume prefetched gathers: accumulate H for sn ----
    if (hasN) {
      const f32x2 a0 = __builtin_amdgcn_cvt_pk_f32_fp8(swn0, false);
      const f32x2 a1 = __builtin_amdgcn_cvt_pk_f32_fp8(swn0, true);
      const f32x2 a2 = __builtin_amdgcn_cvt_pk_f32_fp8(swn1, false);
      const f32x2 a3 = __builtin_amdgcn_cvt_pk_f32_fp8(swn1, true);
      const float sv[8] = {a0[0], a0[1], a1[0], a1[1], a2[0], a2[1], a3[0], a3[1]};
#pragma unroll
      for (int i = 0; i < 8; ++i) hacc[i] = 0.f;
#pragma unroll
      for (int k = 0; k < 16; ++k) {
        const u32x2 zw = (k < 8) ? zbufA[k] : zbufB[k - 8];
        const f32x2 z0 = __builtin_amdgcn_cvt_pk_f32_fp8(zw[0], false);
        const f32x2 z1 = __builtin_amdgcn_cvt_pk_f32_fp8(zw[0], true);
        const f32x2 z2 = __builtin_amdgcn_cvt_pk_f32_fp8(zw[1], false);
        const f32x2 z3 = __builtin_amdgcn_cvt_pk_f32_fp8(zw[1], true);
        hacc[0] += fmaxf(sv[0] + z0[0], 0.f);
        hacc[1] += fmaxf(sv[1] + z0[1], 0.f);
        hacc[2] += fmaxf(sv[2] + z1[0], 0.f);
        hacc[3] += fmaxf(sv[3] + z1[1], 0.f);
        hacc[4] += fmaxf(sv[4] + z2[0], 0.f);
        hacc[5] += fmaxf(sv[5] + z2[1], 0.f);
        hacc[6] += fmaxf(sv[6] + z3[0], 0.f);
        hacc[7] += fmaxf(sv[7] + z3[1], 0.f);
      }
      myidxN = myidxN2;
      trC = trN;
    }
  }
}

extern "C" void kernel_launch(void* const* d_in, const int* in_sizes, int n_in,
                              void* d_out, int out_size, void* d_ws, size_t ws_size,
                              hipStream_t stream)
{
  (void)in_sizes; (void)n_in; (void)out_size; (void)ws_size;
  const float* X   = (const float*)d_in[0];
  const int*   adj = (const int*)d_in[1];
  const float* mW1 = (const float*)d_in[2];
  const float* mb1 = (const float*)d_in[3];
  const float* mW2 = (const float*)d_in[4];
  const float* mb2 = (const float*)d_in[5];
  const float* uW1 = (const float*)d_in[6];
  const float* ub1 = (const float*)d_in[7];
  const float* uW2 = (const float*)d_in[8];
  const float* ub2 = (const float*)d_in[9];
  float* out = (float*)d_out;

  u8* ws8  = (u8*)d_ws;
  u8* Sf8  = ws8;                                // E*ND fp8 (12.8 MB)
  u8* Zf8  = Sf8 + (size_t)NE * ND;              // E*ND fp8 (12.8 MB)
  u16* Tp  = (u16*)(Zf8 + (size_t)NE * ND);      // packed T1 bf16 (25.6 MB, 2048 u16/tile)
  u16* Wi_b = Tp + (size_t)NE * ND;              // 128*128 bf16 each:
  u16* Wj_b = Wi_b + 128 * 128;
  u16* Ui_b = Wj_b + 128 * 128;
  u16* Wp_b = Ui_b + 128 * 128;
  u16* W2_b = Wp_b + 128 * 128;
  float* bp = (float*)(W2_b + 128 * 128);        // 128 f32

  k_prep<<<128, 128, 0, stream>>>(mW1, uW1, uW2, mW2, ub1, mb2,
                                  Wi_b, Wj_b, Ui_b, Wp_b, W2_b, bp);

  k1_szt<<<1024, 512, 0, stream>>>(X, Wi_b, Wj_b, Ui_b, mb1, bp, Sf8, Zf8, Tp);

  k23_fused<<<1024, 512, 0, stream>>>(Zf8, Sf8, adj, Tp, Wp_b, W2_b, ub2, out);
}